// Round 1
// baseline (2773.943 us; speedup 1.0000x reference)
//
#include <hip/hip_runtime.h>

#define NE 8
#define HW 128
#define OUT_HW 384
#define C1 64
#define C2 32
#define C3 9

// Repacked conv2 weights: [e][ic*9 + dy*3 + dx][oc]  (oc contiguous for s_load_dwordx8)
__device__ float g_w2t[NE * 576 * C2];

__global__ void repack_w2_kernel(const float* __restrict__ w2) {
    int i = blockIdx.x * 256 + threadIdx.x;
    const int total = NE * C2 * 576;
    if (i >= total) return;
    int e = i / (C2 * 576);
    int r = i - e * (C2 * 576);
    int oc = r / 576;
    int k = r - oc * 576;          // k = ic*9 + dy*3 + dx
    g_w2t[(e * 576 + k) * C2 + oc] = w2[i];
}

__device__ __forceinline__ float fast_tanh(float x) {
    float ax = fabsf(x);
    float e = __expf(2.0f * ax);                       // inf-safe
    float t = 1.0f - 2.0f * __builtin_amdgcn_rcpf(e + 1.0f);
    return copysignf(t, x);
}

__launch_bounds__(256, 3)
__global__ void espcn_fused_kernel(const float* __restrict__ x,
                                   const int* __restrict__ ci,
                                   const float* __restrict__ w1,
                                   const float* __restrict__ b1,
                                   const float* __restrict__ b2,
                                   const float* __restrict__ w3,
                                   const float* __restrict__ b3,
                                   float* __restrict__ out) {
    __shared__ float xs[16][17];          // x patch (+1 pad col vs bank conflicts)
    __shared__ float h1s[C1][12][12];     // conv1 out (tanh), 12x12 region
    __shared__ float h2s[C2][10][10];     // conv2 out (tanh), 10x10 region

    const int tx = blockIdx.x, ty = blockIdx.y, b = blockIdx.z;
    const int R0 = ty * 8, C0 = tx * 8;
    const int e = ci[b];                  // uniform per block
    const int t = threadIdx.x;
    const int lane = t & 63, wave = t >> 6;

    // ---- phase 0: stage x patch rows [R0-4, R0+12), cols [C0-4, C0+12) ----
    {
        int i = t >> 4, j = t & 15;
        int gy = R0 - 4 + i, gx = C0 - 4 + j;
        float v = 0.f;
        if (gy >= 0 && gy < HW && gx >= 0 && gx < HW)
            v = x[(b * HW + gy) * HW + gx];
        xs[i][j] = v;
    }
    __syncthreads();

    // ---- phase 1: conv1 (5x5, 1->64) + tanh -> h1s (region offset R0-2,C0-2) ----
    {
        const float* w1e = w1 + e * C1 * 25;
        const float* b1e = b1 + e * C1;
        for (int c = wave * 16; c < wave * 16 + 16; ++c) {
            const float bias = b1e[c];
            const float* wc = w1e + c * 25;
            for (int chunk = 0; chunk < 3; ++chunk) {
                int p = chunk * 64 + lane;
                bool valid = p < 144;
                int pc = valid ? p : 143;
                int i = pc / 12, j = pc - i * 12;
                float acc = bias;
                #pragma unroll
                for (int dy = 0; dy < 5; ++dy)
                    #pragma unroll
                    for (int dx = 0; dx < 5; ++dx)
                        acc = fmaf(xs[i + dy][j + dx], wc[dy * 5 + dx], acc);
                int gy = R0 - 2 + i, gx = C0 - 2 + j;
                float val = (gy >= 0 && gy < HW && gx >= 0 && gx < HW) ? fast_tanh(acc) : 0.f;
                if (valid) h1s[c][i][j] = val;
            }
        }
    }
    __syncthreads();

    // ---- phase 2: conv2 (3x3, 64->32) + tanh -> h2s (region offset R0-1,C0-1) ----
    {
        const int oc0 = wave * 8;
        const float* w2e = g_w2t + e * 576 * C2;
        const float* b2e = b2 + e * C2;
        for (int chunk = 0; chunk < 2; ++chunk) {
            int p = chunk * 64 + lane;
            bool valid = p < 100;
            int pc = valid ? p : 99;
            int y = pc / 10, xq = pc - y * 10;
            float acc[8];
            #pragma unroll
            for (int o = 0; o < 8; ++o) acc[o] = b2e[oc0 + o];
            for (int ic = 0; ic < C1; ++ic) {
                #pragma unroll
                for (int k = 0; k < 9; ++k) {
                    float h = h1s[ic][y + k / 3][xq + k % 3];
                    const float* wp = w2e + (ic * 9 + k) * C2 + oc0;
                    #pragma unroll
                    for (int o = 0; o < 8; ++o)
                        acc[o] = fmaf(h, wp[o], acc[o]);
                }
            }
            int gy = R0 - 1 + y, gx = C0 - 1 + xq;
            bool inimg = (gy >= 0 && gy < HW && gx >= 0 && gx < HW);
            if (valid) {
                #pragma unroll
                for (int o = 0; o < 8; ++o)
                    h2s[oc0 + o][y][xq] = inimg ? fast_tanh(acc[o]) : 0.f;
            }
        }
    }
    __syncthreads();

    // ---- phase 3: conv3 (3x3, 32->9) + pixel shuffle write ----
    {
        const float* w3e = w3 + e * C3 * 288;
        const float* b3e = b3 + e * C3;
        const int y = lane >> 3, xq = lane & 7;   // 8x8 output positions, exact wave
        const int nOc = (wave == 3) ? 3 : 2;
        for (int oi = 0; oi < nOc; ++oi) {
            int oc = wave * 2 + oi;               // wave3: 6,7,8
            float acc = b3e[oc];
            const float* wp = w3e + oc * 288;
            for (int ic = 0; ic < C2; ++ic) {
                #pragma unroll
                for (int k = 0; k < 9; ++k)
                    acc = fmaf(h2s[ic][y + k / 3][xq + k % 3], wp[ic * 9 + k], acc);
            }
            int gr = (R0 + y) * 3 + oc / 3;
            int gc = (C0 + xq) * 3 + oc % 3;
            out[(b * OUT_HW + gr) * OUT_HW + gc] = acc;
        }
    }
}

extern "C" void kernel_launch(void* const* d_in, const int* in_sizes, int n_in,
                              void* d_out, int out_size, void* d_ws, size_t ws_size,
                              hipStream_t stream) {
    const float* x  = (const float*)d_in[0];
    const int*   ci = (const int*)  d_in[1];
    const float* w1 = (const float*)d_in[2];
    const float* b1 = (const float*)d_in[3];
    const float* w2 = (const float*)d_in[4];
    const float* b2 = (const float*)d_in[5];
    const float* w3 = (const float*)d_in[6];
    const float* b3 = (const float*)d_in[7];
    float* out = (float*)d_out;

    // 1) repack conv2 weights into [e][ic*9+k][oc] for contiguous scalar loads
    {
        const int total = NE * C2 * 576;
        repack_w2_kernel<<<(total + 255) / 256, 256, 0, stream>>>(w2);
    }
    // 2) fused ESPCN: one block per 8x8 output tile per image
    {
        dim3 grid(HW / 8, HW / 8, 32);
        espcn_fused_kernel<<<grid, 256, 0, stream>>>(x, ci, w1, b1, b2, w3, b3, out);
    }
}

// Round 2
// 413.565 us; speedup vs baseline: 6.7074x; 6.7074x over previous
//
#include <hip/hip_runtime.h>

#define NE 8
#define HW 128
#define OUT_HW 384
#define C1 64
#define C2 32
#define C3 9

typedef __attribute__((ext_vector_type(4))) float f32x4;
typedef __attribute__((ext_vector_type(8))) short bf16x8s;

// Prepacked conv2 weights, bf16: [e][koff(ky*3+kx)][oc][ic]
__device__ __align__(16) unsigned short g_w2b[NE * 9 * C2 * C1];

__device__ __forceinline__ unsigned short f2bf(float f) {
    unsigned u = __builtin_bit_cast(unsigned, f);
    u += 0x7fffu + ((u >> 16) & 1u);          // round-nearest-even
    return (unsigned short)(u >> 16);
}

__global__ void repack_w2b_kernel(const float* __restrict__ w2) {
    int i = blockIdx.x * 256 + threadIdx.x;
    const int total = NE * C2 * C1 * 9;
    if (i >= total) return;
    // source layout: [e][oc][ic][ky][kx]
    int e = i / (C2 * C1 * 9);
    int r = i - e * (C2 * C1 * 9);
    int oc = r / (C1 * 9); r -= oc * (C1 * 9);
    int ic = r / 9;
    int koff = r - ic * 9;
    g_w2b[((e * 9 + koff) * C2 + oc) * C1 + ic] = f2bf(w2[i]);
}

__device__ __forceinline__ float fast_tanh(float x) {
    float ax = fabsf(x);
    float ex = __expf(2.0f * ax);                       // inf-safe
    float tv = 1.0f - 2.0f * __builtin_amdgcn_rcpf(ex + 1.0f);
    return copysignf(tv, x);
}

__launch_bounds__(256, 4)
__global__ void espcn_fused_kernel(const float* __restrict__ x,
                                   const int* __restrict__ ci,
                                   const float* __restrict__ w1,
                                   const float* __restrict__ b1,
                                   const float* __restrict__ b2,
                                   const float* __restrict__ w3,
                                   const float* __restrict__ b3,
                                   float* __restrict__ out) {
    __shared__ float xs[16][17];                            // x patch
    __shared__ __align__(16) unsigned short h1s[144 * 64];  // [pixel][ic] bf16, XOR-swizzled
    __shared__ float h2s[C2][100];                          // [oc][pixel] f32

    const int tx = blockIdx.x, ty = blockIdx.y, b = blockIdx.z;
    const int R0 = ty * 8, C0 = tx * 8;
    int e = ci[b];
    e = __builtin_amdgcn_readfirstlane(e);                  // force SGPR: scalar weight loads
    const int t = threadIdx.x;
    const int lane = t & 63, wave = t >> 6;

    // ---- phase 0: stage x patch rows [R0-4, R0+12), cols [C0-4, C0+12) ----
    {
        int i = t >> 4, j = t & 15;
        int gy = R0 - 4 + i, gx = C0 - 4 + j;
        float v = 0.f;
        if (gy >= 0 && gy < HW && gx >= 0 && gx < HW)
            v = x[(b * HW + gy) * HW + gx];
        xs[i][j] = v;
    }
    __syncthreads();

    // ---- phase 1: conv1 (5x5, 1->64) + tanh -> h1s[pixel][ic] bf16 ----
    // 768 tasks = 64 channels x 12 columns; 3 tasks per thread.
    {
        const float* w1e = w1 + e * C1 * 25;
        const float* b1e = b1 + e * C1;
        #pragma unroll
        for (int it = 0; it < 3; ++it) {
            int task = it * 256 + t;
            int c = task / 12, j = task - c * 12;
            float wreg[25];
            #pragma unroll
            for (int q = 0; q < 25; ++q) wreg[q] = w1e[c * 25 + q];
            float bias = b1e[c];
            float acc[12];
            #pragma unroll
            for (int r = 0; r < 12; ++r) acc[r] = bias;
            #pragma unroll
            for (int i = 0; i < 16; ++i) {
                float v0 = xs[i][j], v1 = xs[i][j + 1], v2 = xs[i][j + 2],
                      v3 = xs[i][j + 3], v4 = xs[i][j + 4];
                #pragma unroll
                for (int dy = 0; dy < 5; ++dy) {
                    int r = i - dy;
                    if (r >= 0 && r < 12) {
                        acc[r] = fmaf(v0, wreg[dy * 5 + 0], acc[r]);
                        acc[r] = fmaf(v1, wreg[dy * 5 + 1], acc[r]);
                        acc[r] = fmaf(v2, wreg[dy * 5 + 2], acc[r]);
                        acc[r] = fmaf(v3, wreg[dy * 5 + 3], acc[r]);
                        acc[r] = fmaf(v4, wreg[dy * 5 + 4], acc[r]);
                    }
                }
            }
            #pragma unroll
            for (int r = 0; r < 12; ++r) {
                int gy = R0 - 2 + r, gx = C0 - 2 + j;
                float val = (gy >= 0 && gy < HW && gx >= 0 && gx < HW) ? fast_tanh(acc[r]) : 0.f;
                int p = r * 12 + j;
                int off = ((p << 7) + (c << 1)) ^ ((p & 7) << 4);
                *(unsigned short*)((char*)h1s + off) = f2bf(val);
            }
        }
    }
    __syncthreads();

    // ---- phase 2: conv2 (3x3, 64->32) as bf16 MFMA + tanh -> h2s ----
    // M = 100 pixels (8 tiles of 16, padded), N = 32 oc (2 tiles), K = 576 (18 steps of 32).
    {
        const unsigned short* w2e = g_w2b + e * 9 * C2 * C1;
        const int g = lane >> 4, r16 = lane & 15;
        int ps0 = wave * 32 + r16;       if (ps0 > 99) ps0 = 99;
        int ps1 = wave * 32 + 16 + r16;  if (ps1 > 99) ps1 = 99;
        const int ab0 = (ps0 / 10) * 12 + (ps0 % 10);
        const int ab1 = (ps1 / 10) * 12 + (ps1 % 10);
        f32x4 acc00 = {0.f, 0.f, 0.f, 0.f}, acc01 = {0.f, 0.f, 0.f, 0.f};
        f32x4 acc10 = {0.f, 0.f, 0.f, 0.f}, acc11 = {0.f, 0.f, 0.f, 0.f};
        const int laneB = (r16 * C1 + g * 8);          // elements
        #pragma unroll
        for (int s = 0; s < 18; ++s) {
            const int koff = s >> 1;
            const int drow = (koff / 3) * 12 + (koff % 3);
            const int icoff2 = ((s & 1) * 32 + g * 8) * 2;
            int r0 = ab0 + drow, r1 = ab1 + drow;
            int o0 = ((r0 << 7) + icoff2) ^ ((r0 & 7) << 4);
            int o1 = ((r1 << 7) + icoff2) ^ ((r1 & 7) << 4);
            bf16x8s A0 = *(const bf16x8s*)((const char*)h1s + o0);
            bf16x8s A1 = *(const bf16x8s*)((const char*)h1s + o1);
            const unsigned short* wp = w2e + koff * C2 * C1 + (s & 1) * 32;
            bf16x8s B0 = *(const bf16x8s*)(wp + laneB);
            bf16x8s B1 = *(const bf16x8s*)(wp + 16 * C1 + laneB);
            acc00 = __builtin_amdgcn_mfma_f32_16x16x32_bf16(A0, B0, acc00, 0, 0, 0);
            acc01 = __builtin_amdgcn_mfma_f32_16x16x32_bf16(A0, B1, acc01, 0, 0, 0);
            acc10 = __builtin_amdgcn_mfma_f32_16x16x32_bf16(A1, B0, acc10, 0, 0, 0);
            acc11 = __builtin_amdgcn_mfma_f32_16x16x32_bf16(A1, B1, acc11, 0, 0, 0);
        }
        // epilogue: D row = (lane>>4)*4 + reg (pixel), col = lane&15 (oc)
        const float* b2e = b2 + e * C2;
        float bias0 = b2e[r16], bias1 = b2e[16 + r16];
        #pragma unroll
        for (int m = 0; m < 2; ++m) {
            f32x4 aN0 = m ? acc10 : acc00;
            f32x4 aN1 = m ? acc11 : acc01;
            int mtbase = wave * 32 + m * 16;
            #pragma unroll
            for (int q = 0; q < 4; ++q) {
                int pd = mtbase + g * 4 + q;
                if (pd < 100) {
                    int y = pd / 10, xq2 = pd - y * 10;
                    int gy = R0 - 1 + y, gx = C0 - 1 + xq2;
                    bool inimg = (gy >= 0 && gy < HW && gx >= 0 && gx < HW);
                    h2s[r16][pd]      = inimg ? fast_tanh(aN0[q] + bias0) : 0.f;
                    h2s[16 + r16][pd] = inimg ? fast_tanh(aN1[q] + bias1) : 0.f;
                }
            }
        }
    }
    __syncthreads();

    // ---- phase 3: conv3 (3x3, 32->9) + pixel shuffle write ----
    {
        const float* w3e = w3 + e * C3 * 288;
        const float* b3e = b3 + e * C3;
        const int y = lane >> 3, xq = lane & 7;
        const int nOc = (wave == 3) ? 3 : 2;
        for (int oi = 0; oi < nOc; ++oi) {
            int oc = wave * 2 + oi;
            float acc = b3e[oc];
            const float* wp = w3e + oc * 288;
            for (int ic = 0; ic < C2; ++ic) {
                #pragma unroll
                for (int k = 0; k < 9; ++k)
                    acc = fmaf(h2s[ic][(y + k / 3) * 10 + (xq + k % 3)], wp[ic * 9 + k], acc);
            }
            int gr = (R0 + y) * 3 + oc / 3;
            int gc = (C0 + xq) * 3 + oc % 3;
            out[(b * OUT_HW + gr) * OUT_HW + gc] = acc;
        }
    }
}

extern "C" void kernel_launch(void* const* d_in, const int* in_sizes, int n_in,
                              void* d_out, int out_size, void* d_ws, size_t ws_size,
                              hipStream_t stream) {
    const float* x  = (const float*)d_in[0];
    const int*   ci = (const int*)  d_in[1];
    const float* w1 = (const float*)d_in[2];
    const float* b1 = (const float*)d_in[3];
    const float* w2 = (const float*)d_in[4];
    const float* b2 = (const float*)d_in[5];
    const float* w3 = (const float*)d_in[6];
    const float* b3 = (const float*)d_in[7];
    float* out = (float*)d_out;

    {
        const int total = NE * C2 * C1 * 9;
        repack_w2b_kernel<<<(total + 255) / 256, 256, 0, stream>>>(w2);
    }
    {
        dim3 grid(HW / 8, HW / 8, 32);
        espcn_fused_kernel<<<grid, 256, 0, stream>>>(x, ci, w1, b1, b2, w3, b3, out);
    }
}